// Round 1
// baseline (1056.502 us; speedup 1.0000x reference)
//
#include <hip/hip_runtime.h>
#include <hip/hip_bf16.h>
#include <math.h>

// Problem constants (from reference)
#define BB 64
#define TT 4096
#define II 128
#define HH 256
#define LL 512           // chunk length
#define CC 8             // chunks = TT/LL

// ws layout (floats):
//   ypart : 4*BB*TT     (per-wave partial y, zero-init-state local scan)
//   Mlocal: BB*CC*HH    (chunk-local end states)
//   Minit : BB*CC*HH    (true state at each chunk start)
//   Apow  : HH*LL       (A[h][k] = alpha_h^(k+1))

// ---------------- K0: powers table ----------------
__global__ __launch_bounds__(256) void k0_pow(const float* __restrict__ tau,
                                              float* __restrict__ Apow) {
    int idx = blockIdx.x * 256 + threadIdx.x;   // over HH*LL
    int h = idx / LL, k = idx % LL;
    float a = 1.0f / (1.0f + expf(-tau[h]));
    // a^(k+1) via exp2; exact enough (rel err ~1e-5 at k=511)
    float l2a = (a > 0.0f) ? log2f(a) : -1e30f;
    Apow[idx] = exp2f((float)(k + 1) * l2a);
}

// ---------------- K1: fused GEMM + local scan ----------------
// grid = BB*CC blocks, 256 threads (thread = channel h)
__global__ __launch_bounds__(256, 2) void k1_scan(
    const float* __restrict__ x, const float* __restrict__ Wd,
    const float* __restrict__ bd, const float* __restrict__ Wo,
    const float* __restrict__ tau,
    float* __restrict__ ypart, float* __restrict__ Mlocal)
{
    const int blk = blockIdx.x;
    const int b = blk / CC, c = blk % CC;
    const int tid = threadIdx.x;           // h
    const int lane = tid & 63, wave = tid >> 6;

    const float a   = 1.0f / (1.0f + expf(-tau[tid]));
    const float oma = 1.0f - a;
    const float wo  = Wo[tid];
    const float bdh = bd[tid];

    // cache this thread's Wd row (128 f32) in registers
    float4 wd[32];
    const float4* wrow = reinterpret_cast<const float4*>(Wd + (size_t)tid * II);
#pragma unroll
    for (int i = 0; i < 32; ++i) wd[i] = wrow[i];

    float mem = 0.0f;
    float ykeep = 0.0f;
    const int t0 = c * LL;
    float* yp = ypart + ((size_t)wave * BB * TT) + (size_t)b * TT + t0;

    for (int tg = 0; tg < LL / 64; ++tg) {
#pragma unroll 2
        for (int tt = 0; tt < 64; ++tt) {
            const int t = t0 + tg * 64 + tt;
            // wave-uniform address -> scalar/broadcast loads
            const float4* xt = reinterpret_cast<const float4*>(
                x + ((size_t)b * TT + t) * II);
            float a0 = 0.f, a1 = 0.f, a2 = 0.f, a3 = 0.f;
#pragma unroll
            for (int i = 0; i < 32; ++i) {
                float4 xv = xt[i];
                a0 = fmaf(wd[i].x, xv.x, a0);
                a1 = fmaf(wd[i].y, xv.y, a1);
                a2 = fmaf(wd[i].z, xv.z, a2);
                a3 = fmaf(wd[i].w, xv.w, a3);
            }
            float cval = (a0 + a1) + (a2 + a3) + bdh;
            mem = a * mem + oma * cval;
            // reduce wo*mem over the 64 lanes (64 channels) of this wave
            float s = wo * mem;
            s += __shfl_xor(s, 1);
            s += __shfl_xor(s, 2);
            s += __shfl_xor(s, 4);
            s += __shfl_xor(s, 8);
            s += __shfl_xor(s, 16);
            s += __shfl_xor(s, 32);
            if (lane == tt) ykeep = s;   // lane tt keeps y(t) for this wave
        }
        yp[lane] = ykeep;                 // coalesced: 64 consecutive t
        yp += 64;
    }
    Mlocal[((size_t)b * CC + c) * HH + tid] = mem;
}

// ---------------- K2: chunk-level state chain ----------------
// grid = BB*HH/256 blocks
__global__ __launch_bounds__(256) void k2_chain(
    const float* __restrict__ Mlocal, const float* __restrict__ Apow,
    float* __restrict__ Minit)
{
    int idx = blockIdx.x * 256 + threadIdx.x;   // over BB*HH
    int b = idx / HH, h = idx % HH;
    float aL = Apow[(size_t)h * LL + (LL - 1)];   // a^LL
    float M = 0.0f;
#pragma unroll
    for (int c = 0; c < CC; ++c) {
        size_t o = ((size_t)b * CC + c) * HH + h;
        Minit[o] = M;
        M = aL * M + Mlocal[o];
    }
}

// ---------------- K3: fixup + output ----------------
// grid = BB*CC blocks, 256 threads
__global__ __launch_bounds__(256) void k3_out(
    const float* __restrict__ ypart, const float* __restrict__ Minit,
    const float* __restrict__ Apow, const float* __restrict__ Wo,
    const float* __restrict__ bo, float* __restrict__ out)
{
    __shared__ float wc[HH];
    const int blk = blockIdx.x;
    const int b = blk / CC, c = blk % CC;
    const int tid = threadIdx.x;

    wc[tid] = Wo[tid] * Minit[((size_t)b * CC + c) * HH + tid];
    __syncthreads();

    const float bov = bo[0];
    const size_t NT = (size_t)BB * TT;
#pragma unroll
    for (int r = 0; r < 2; ++r) {
        int k = r * 256 + tid;
        float corr = 0.0f;
#pragma unroll 4
        for (int h = 0; h < HH; ++h)
            corr = fmaf(wc[h], Apow[(size_t)h * LL + k], corr);
        size_t t = (size_t)b * TT + (size_t)c * LL + k;
        float y = ypart[t] + ypart[NT + t] + ypart[2 * NT + t] + ypart[3 * NT + t];
        float z = y + corr + bov;
        out[t] = 1.0f / (1.0f + expf(-z));
    }
}

extern "C" void kernel_launch(void* const* d_in, const int* in_sizes, int n_in,
                              void* d_out, int out_size, void* d_ws, size_t ws_size,
                              hipStream_t stream) {
    const float* x   = (const float*)d_in[0];
    const float* Wd  = (const float*)d_in[1];
    const float* bd  = (const float*)d_in[2];
    const float* Wo  = (const float*)d_in[3];
    const float* bo  = (const float*)d_in[4];
    const float* tau = (const float*)d_in[5];
    float* out = (float*)d_out;

    float* ws     = (float*)d_ws;
    float* ypart  = ws;                                   // 4*BB*TT
    float* Mlocal = ypart + (size_t)4 * BB * TT;          // BB*CC*HH
    float* Minit  = Mlocal + (size_t)BB * CC * HH;        // BB*CC*HH
    float* Apow   = Minit + (size_t)BB * CC * HH;         // HH*LL

    k0_pow<<<(HH * LL) / 256, 256, 0, stream>>>(tau, Apow);
    k1_scan<<<BB * CC, 256, 0, stream>>>(x, Wd, bd, Wo, tau, ypart, Mlocal);
    k2_chain<<<(BB * HH) / 256, 256, 0, stream>>>(Mlocal, Apow, Minit);
    k3_out<<<BB * CC, 256, 0, stream>>>(ypart, Minit, Apow, Wo, bo, out);
}

// Round 2
// 313.408 us; speedup vs baseline: 3.3710x; 3.3710x over previous
//
#include <hip/hip_runtime.h>
#include <hip/hip_bf16.h>
#include <math.h>

#define BB 64
#define TT 4096
#define II 128
#define HH 256
#define L2C 128          // chunk length
#define C2 32            // chunks = TT/L2C

typedef __attribute__((ext_vector_type(8))) short short8;   // 8 bf16 (4 VGPRs)
typedef __attribute__((ext_vector_type(4))) float f32x4;

__device__ inline ushort f2b(float f) {
    __hip_bfloat16 h = __float2bfloat16(f);
    return *reinterpret_cast<ushort*>(&h);
}
__device__ inline float b2f(ushort u) {
    unsigned v = ((unsigned)u) << 16;
    union { unsigned u; float f; } c; c.u = v; return c.f;
}

// ---------------- K0: tables ----------------
// grid 128 x 256 (idx over 32768)
__global__ __launch_bounds__(256) void k0_tables(
    const float* __restrict__ Wd, const float* __restrict__ bd,
    const float* __restrict__ Wo, const float* __restrict__ tau,
    ushort* __restrict__ Wdb, ushort* __restrict__ Vt,
    float* __restrict__ Apow, float* __restrict__ alphas,
    float* __restrict__ mb, float* __restrict__ ybias)
{
    int idx = blockIdx.x * 256 + threadIdx.x;
    // task A: Wd -> bf16, same [h][i] layout
    Wdb[idx] = f2b(Wd[idx]);
    // task B: Vt[d][h] = Wo[h]*(1-a)*a^d
    {
        int d = idx >> 8, h = idx & 255;
        float a = 1.0f / (1.0f + expf(-tau[h]));
        float ad = exp2f((float)d * log2f(a));      // a^d (d=0 -> 1)
        Vt[idx] = f2b(Wo[h] * (1.0f - a) * ad);
    }
    // task C: Apow[h][k] = a^(k+1), k=0..127
    {
        int h = idx >> 7, k = idx & 127;
        float a = 1.0f / (1.0f + expf(-tau[h]));
        Apow[idx] = exp2f((float)(k + 1) * log2f(a));
    }
    // task E: alphas, mb
    if (idx < HH) {
        float a = 1.0f / (1.0f + expf(-tau[idx]));
        alphas[idx] = a;
        float aL = exp2f(128.0f * log2f(a));
        mb[idx] = bd[idx] * (1.0f - aL);
    }
    // task D: ybias[k] = sum_h Wo*bd*(1-a^(k+1))
    if (idx < L2C) {
        float s = 0.0f;
        for (int h = 0; h < HH; ++h) {
            float a = 1.0f / (1.0f + expf(-tau[h]));
            float apk = exp2f((float)(idx + 1) * log2f(a));
            s += Wo[h] * bd[h] * (1.0f - apk);
        }
        ybias[idx] = s;
    }
}

// ---------------- K1: fused MFMA GEMM + MFMA scan ----------------
// grid = BB*C2 = 2048 blocks, 256 threads (4 waves)
// LDS: region0 [0,34816): As (x tile bf16, 128 x 136) then curhalf (128 x 136) then P (128 x 132)
//      mpart   [34816, 35328): 128 f32
__global__ __launch_bounds__(256, 2) void k1_fused(
    const float* __restrict__ x, const ushort* __restrict__ Wdb,
    const ushort* __restrict__ Vt, const float* __restrict__ alphas,
    const float* __restrict__ mb, const float* __restrict__ Apow,
    float* __restrict__ ypart, float* __restrict__ Mlocal)
{
    __shared__ __align__(16) char smem[35328];
    ushort* reg0  = reinterpret_cast<ushort*>(smem);          // As / curhalf / P
    float*  mpart = reinterpret_cast<float*>(smem + 34816);

    const int blk = blockIdx.x;
    const int b = blk >> 5, tc = blk & 31;
    const int tid = threadIdx.x;
    const int lane = tid & 63, w = tid >> 6;
    const int l15 = lane & 15, quad = lane >> 4;
    const int t0 = tc * L2C;

    // ---- stage x chunk (128t x 128i f32) -> bf16 LDS As[t][i], stride 136 ----
    {
        const float4* xg = reinterpret_cast<const float4*>(x + ((size_t)b * TT + t0) * II);
#pragma unroll
        for (int it = 0; it < 16; ++it) {
            int fl = it * 256 + tid;            // float4 index over 4096
            int t = fl >> 5, i4 = fl & 31;
            float4 v = xg[t * 32 + i4];
            ushort4 u;
            u.x = f2b(v.x); u.y = f2b(v.y); u.z = f2b(v.z); u.w = f2b(v.w);
            *reinterpret_cast<ushort4*>(&reg0[t * 136 + i4 * 4]) = u;
        }
    }
    __syncthreads();

    // ---- preload A fragments: afr[mt][kt], t-rows trow..trow+63 ----
    const int trow = (w & 1) * 64;        // MFMA1 m (t) rows for this wave
    const int hsel = (w >> 1) * 64;       // MFMA1 n (h within half) cols
    short8 afr[4][4];
#pragma unroll
    for (int mt = 0; mt < 4; ++mt)
#pragma unroll
        for (int kt = 0; kt < 4; ++kt) {
            int t = trow + mt * 16 + l15;
            int i = kt * 32 + quad * 8;
            afr[mt][kt] = *reinterpret_cast<const short8*>(&reg0[t * 136 + i]);
        }

    const int srow = (w & 1) * 64;        // MFMA2 m (s) rows
    const int dcol = (w >> 1) * 64;       // MFMA2 n (d) cols
    f32x4 acc2[4][4];
#pragma unroll
    for (int mt = 0; mt < 4; ++mt)
#pragma unroll
        for (int nt = 0; nt < 4; ++nt)
            acc2[mt][nt] = (f32x4){0.f, 0.f, 0.f, 0.f};

    // h-index of this thread for the Mlocal phase
    const int hl_m = tid & 127, sh_m = tid >> 7;

#pragma unroll 1
    for (int hh = 0; hh < 2; ++hh) {
        // ---- MFMA1: cur-half = x @ Wd^T for h in [hh*128, hh*128+128) ----
        f32x4 acc1[4][4];
#pragma unroll
        for (int mt = 0; mt < 4; ++mt)
#pragma unroll
            for (int nt = 0; nt < 4; ++nt)
                acc1[mt][nt] = (f32x4){0.f, 0.f, 0.f, 0.f};

#pragma unroll
        for (int kt = 0; kt < 4; ++kt) {
            short8 bf[4];
#pragma unroll
            for (int nt = 0; nt < 4; ++nt) {
                int h = hh * 128 + hsel + nt * 16 + l15;
                int i = kt * 32 + quad * 8;
                bf[nt] = *reinterpret_cast<const short8*>(&Wdb[h * 128 + i]);
            }
#pragma unroll
            for (int mt = 0; mt < 4; ++mt)
#pragma unroll
                for (int nt = 0; nt < 4; ++nt)
                    acc1[mt][nt] = __builtin_amdgcn_mfma_f32_16x16x32_bf16(
                        afr[mt][kt], bf[nt], acc1[mt][nt], 0, 0, 0);
        }

        // sync A: previous-half readers done (and A-frag preload done for hh=0)
        __syncthreads();

        // ---- write cur-half to LDS: curhalf[t][hl], stride 136, bf16 ----
#pragma unroll
        for (int mt = 0; mt < 4; ++mt)
#pragma unroll
            for (int nt = 0; nt < 4; ++nt) {
                int hl = hsel + nt * 16 + l15;
#pragma unroll
                for (int r = 0; r < 4; ++r) {
                    int t = trow + mt * 16 + quad * 4 + r;
                    reg0[t * 136 + hl] = f2b(acc1[mt][nt][r]);
                }
            }
        __syncthreads();   // sync B: cur-half visible

        // ---- Mlocal partial (thread: hl_m, s-range by sh_m) ----
        {
            int h = hh * 128 + hl_m;
            float a = alphas[h];
            float wgt = 1.0f - a;
            float M = 0.0f;
            int send = sh_m * 64 + 63;
#pragma unroll 4
            for (int s = send; s >= sh_m * 64; --s) {
                float cv = b2f(reg0[s * 136 + hl_m]);
                M = fmaf(wgt, cv, M);
                wgt *= a;
            }
            if (sh_m == 0) {
                // low-half sum needs extra a^64 = Apow[h][63]
                mpart[hl_m] = M * Apow[h * 128 + 63];
            } else {
                mpart[128 + 0] = mpart[128 + 0]; // no-op keep structure
            }
            // stash M for sh_m==1 path; store after sync C
            // (kept in register: M)
            // ---- MFMA2 partial: P += cur-half @ V-half ----
#pragma unroll
            for (int kk = 0; kk < 4; ++kk) {
                short8 a2[4];
#pragma unroll
                for (int mt = 0; mt < 4; ++mt) {
                    int s = srow + mt * 16 + l15;
                    a2[mt] = *reinterpret_cast<const short8*>(
                        &reg0[s * 136 + kk * 32 + quad * 8]);
                }
                short8 b2[4];
#pragma unroll
                for (int nt = 0; nt < 4; ++nt) {
                    int d = dcol + nt * 16 + l15;
                    int hk = hh * 128 + kk * 32 + quad * 8;
                    b2[nt] = *reinterpret_cast<const short8*>(&Vt[d * 256 + hk]);
                }
#pragma unroll
                for (int mt = 0; mt < 4; ++mt)
#pragma unroll
                    for (int nt = 0; nt < 4; ++nt)
                        acc2[mt][nt] = __builtin_amdgcn_mfma_f32_16x16x32_bf16(
                            a2[mt], b2[nt], acc2[mt][nt], 0, 0, 0);
            }
            __syncthreads();  // sync C: mpart visible; cur-half reads complete
            if (sh_m == 1) {
                int hglob = hh * 128 + hl_m;
                float Mfull = M + mpart[hl_m] + mb[hglob];
                Mlocal[((size_t)b * C2 + tc) * HH + hglob] = Mfull;
            }
        }
    }

    // ---- write P (128s x 128d) to LDS bf16, stride 132 ----
#pragma unroll
    for (int mt = 0; mt < 4; ++mt)
#pragma unroll
        for (int nt = 0; nt < 4; ++nt) {
            int d = dcol + nt * 16 + l15;
#pragma unroll
            for (int r = 0; r < 4; ++r) {
                int s = srow + mt * 16 + quad * 4 + r;
                reg0[s * 132 + d] = f2b(acc2[mt][nt][r]);
            }
        }
    __syncthreads();

    // ---- anti-diagonal sums: y[t] = sum_{s<=t} P[s][t-s] ----
    if (tid < 128) {
        int k = tid;
        float y = 0.0f;
        for (int s = 0; s <= k; ++s)
            y += b2f(reg0[s * 132 + (k - s)]);
        ypart[(size_t)b * TT + t0 + k] = y;
    }
}

// ---------------- K2: chunk-level state chain ----------------
// grid = BB*HH/256 = 64 blocks
__global__ __launch_bounds__(256) void k2_chain(
    const float* __restrict__ Mlocal, const float* __restrict__ Apow,
    float* __restrict__ Minit)
{
    int idx = blockIdx.x * 256 + threadIdx.x;   // over BB*HH
    int b = idx >> 8, h = idx & 255;
    float aL = Apow[h * 128 + 127];             // a^128
    float M = 0.0f;
#pragma unroll
    for (int c = 0; c < C2; ++c) {
        size_t o = ((size_t)b * C2 + c) * HH + h;
        Minit[o] = M;
        M = aL * M + Mlocal[o];
    }
}

// ---------------- K3: fixup + bias + sigmoid ----------------
// grid = BB*C2 = 2048 blocks, 128 threads
__global__ __launch_bounds__(128) void k3_out(
    const float* __restrict__ ypart, const float* __restrict__ Minit,
    const float* __restrict__ Apow, const float* __restrict__ Wo,
    const float* __restrict__ bo, const float* __restrict__ ybias,
    float* __restrict__ out)
{
    __shared__ float wc[HH];
    const int blk = blockIdx.x;
    const int b = blk >> 5, c = blk & 31;
    const int tid = threadIdx.x;

    wc[tid]       = Wo[tid]       * Minit[((size_t)b * C2 + c) * HH + tid];
    wc[tid + 128] = Wo[tid + 128] * Minit[((size_t)b * C2 + c) * HH + tid + 128];
    __syncthreads();

    const int k = tid;
    float corr = 0.0f;
#pragma unroll 8
    for (int h = 0; h < HH; ++h)
        corr = fmaf(wc[h], Apow[h * 128 + k], corr);
    size_t t = (size_t)b * TT + (size_t)c * L2C + k;
    float z = ypart[t] + corr + ybias[k] + bo[0];
    out[t] = 1.0f / (1.0f + expf(-z));
}

extern "C" void kernel_launch(void* const* d_in, const int* in_sizes, int n_in,
                              void* d_out, int out_size, void* d_ws, size_t ws_size,
                              hipStream_t stream) {
    const float* x   = (const float*)d_in[0];
    const float* Wd  = (const float*)d_in[1];
    const float* bd  = (const float*)d_in[2];
    const float* Wo  = (const float*)d_in[3];
    const float* bo  = (const float*)d_in[4];
    const float* tau = (const float*)d_in[5];
    float* out = (float*)d_out;

    float* ws = (float*)d_ws;
    float*  ypart  = ws;                         // 262144
    float*  Mlocal = ws + 262144;                // 524288
    float*  Minit  = ws + 786432;                // 524288
    float*  Apow   = ws + 1310720;               // 32768
    float*  alphas = ws + 1343488;               // 256
    float*  mb     = ws + 1343744;               // 256
    float*  ybias  = ws + 1344000;               // 256 (128 used)
    ushort* Wdb    = (ushort*)(ws + 1344256);    // 32768 bf16
    ushort* Vt     = (ushort*)(ws + 1360640);    // 32768 bf16

    k0_tables<<<128, 256, 0, stream>>>(Wd, bd, Wo, tau, Wdb, Vt, Apow, alphas, mb, ybias);
    k1_fused<<<BB * C2, 256, 0, stream>>>(x, Wdb, Vt, alphas, mb, Apow, ypart, Mlocal);
    k2_chain<<<BB * HH / 256, 256, 0, stream>>>(Mlocal, Apow, Minit);
    k3_out<<<BB * C2, 128, 0, stream>>>(ypart, Minit, Apow, Wo, bo, ybias, out);
}